// Round 1
// baseline (1166.845 us; speedup 1.0000x reference)
//
#include <hip/hip_runtime.h>
#include <hip/hip_bf16.h>
#include <math.h>

#define D 256
#define NCAM 500
#define NPT 100000

// ---------------- scatter-add: one edge per block, thread = feature ----------
__global__ void scatter_kernel(const float* __restrict__ ef,
                               const int* __restrict__ ci,
                               const int* __restrict__ pi,
                               float* __restrict__ cam_agg,
                               float* __restrict__ pt_agg, int E) {
    int e = blockIdx.x;
    if (e >= E) return;
    int c = ci[e];
    int p = pi[e];
    int f = threadIdx.x;
    float v = ef[(size_t)e * D + f];
    atomicAdd(&pt_agg[(size_t)p * D + f], v);
    atomicAdd(&cam_agg[(size_t)c * D + f], v);
}

// ---------------- fold weights:
// CcamT[i*256+o] = sum_j Wfin[o,j]      * Wcam[j,i]   (transposed store for cam_proj)
// Cpt  [o*256+i] = sum_j Wfin[o,256+j]  * Wpt[j,i]    (row-major for GEMM)
// vcam[i] = sum_j Wattn[j]    * Wcam[j,i]
// vpt [i] = sum_j Wattn[256+j]* Wpt[j,i]
__global__ void combine_weights(const float* __restrict__ Wcam,
                                const float* __restrict__ Wpt,
                                const float* __restrict__ Wattn,
                                const float* __restrict__ Wfin,
                                float* __restrict__ CcamT,
                                float* __restrict__ Cpt,
                                float* __restrict__ vcam,
                                float* __restrict__ vpt) {
    int b = blockIdx.x;
    int i = threadIdx.x;
    if (b < 256) {
        int o = b;
        float acc = 0.f;
        for (int j = 0; j < 256; j++) acc += Wfin[o * 512 + j] * Wcam[j * 256 + i];
        CcamT[i * 256 + o] = acc;
    } else if (b < 512) {
        int o = b - 256;
        float acc = 0.f;
        for (int j = 0; j < 256; j++) acc += Wfin[o * 512 + 256 + j] * Wpt[j * 256 + i];
        Cpt[o * 256 + i] = acc;
    } else if (b == 512) {
        float acc = 0.f;
        for (int j = 0; j < 256; j++) acc += Wattn[j] * Wcam[j * 256 + i];
        vcam[i] = acc;
    } else {
        float acc = 0.f;
        for (int j = 0; j < 256; j++) acc += Wattn[256 + j] * Wpt[j * 256 + i];
        vpt[i] = acc;
    }
}

// ---------------- cam projection: 500 blocks, thread = output o -------------
__global__ void cam_proj(const float* __restrict__ cam_agg,
                         const float* __restrict__ CcamT,
                         const float* __restrict__ vcam,
                         float* __restrict__ gcam,
                         float* __restrict__ acam) {
    __shared__ float row[256];
    __shared__ float red[256];
    int c = blockIdx.x;
    int t = threadIdx.x;
    row[t] = cam_agg[(size_t)c * 256 + t];
    __syncthreads();
    float acc = 0.f;
    for (int i = 0; i < 256; i++) acc += row[i] * CcamT[i * 256 + t];  // coalesced over t
    gcam[(size_t)c * 256 + t] = acc;
    red[t] = row[t] * vcam[t];
    __syncthreads();
    for (int s = 128; s > 0; s >>= 1) {
        if (t < s) red[t] += red[t + s];
        __syncthreads();
    }
    if (t == 0) acam[c] = red[0];
}

// ---------------- main GEMM: g_pt[M,256] = A[M,256] @ B[256,256]^T ----------
#define BM 64
#define BN 64
#define BK 32
__global__ __launch_bounds__(256) void gemm_pt(const float* __restrict__ A,
                                               const float* __restrict__ Bmat,
                                               float* __restrict__ Cout, int M) {
    __shared__ float As[BK][BM + 4];
    __shared__ float Bs[BK][BN + 4];
    int m0 = blockIdx.x * BM;
    int n0 = blockIdx.y * BN;
    int tid = threadIdx.x;
    int arow = tid >> 2;            // 0..63
    int acol = (tid & 3) * 8;       // 0,8,16,24
    int tm = (tid >> 4) << 2;       // 0..60
    int tn = (tid & 15) << 2;       // 0..60
    float acc[4][4] = {};
    for (int k0 = 0; k0 < 256; k0 += BK) {
        const float* aptr = A + (size_t)(m0 + arow) * 256 + k0 + acol;
        float4 av0 = *(const float4*)aptr;
        float4 av1 = *(const float4*)(aptr + 4);
        const float* bptr = Bmat + (size_t)(n0 + arow) * 256 + k0 + acol;
        float4 bv0 = *(const float4*)bptr;
        float4 bv1 = *(const float4*)(bptr + 4);
        As[acol + 0][arow] = av0.x; As[acol + 1][arow] = av0.y;
        As[acol + 2][arow] = av0.z; As[acol + 3][arow] = av0.w;
        As[acol + 4][arow] = av1.x; As[acol + 5][arow] = av1.y;
        As[acol + 6][arow] = av1.z; As[acol + 7][arow] = av1.w;
        Bs[acol + 0][arow] = bv0.x; Bs[acol + 1][arow] = bv0.y;
        Bs[acol + 2][arow] = bv0.z; Bs[acol + 3][arow] = bv0.w;
        Bs[acol + 4][arow] = bv1.x; Bs[acol + 5][arow] = bv1.y;
        Bs[acol + 6][arow] = bv1.z; Bs[acol + 7][arow] = bv1.w;
        __syncthreads();
#pragma unroll
        for (int k = 0; k < BK; k++) {
            float4 a = *(const float4*)&As[k][tm];
            float4 b = *(const float4*)&Bs[k][tn];
            acc[0][0] += a.x * b.x; acc[0][1] += a.x * b.y; acc[0][2] += a.x * b.z; acc[0][3] += a.x * b.w;
            acc[1][0] += a.y * b.x; acc[1][1] += a.y * b.y; acc[1][2] += a.y * b.z; acc[1][3] += a.y * b.w;
            acc[2][0] += a.z * b.x; acc[2][1] += a.z * b.y; acc[2][2] += a.z * b.z; acc[2][3] += a.z * b.w;
            acc[3][0] += a.w * b.x; acc[3][1] += a.w * b.y; acc[3][2] += a.w * b.z; acc[3][3] += a.w * b.w;
        }
        __syncthreads();
    }
#pragma unroll
    for (int i = 0; i < 4; i++) {
        int m = m0 + tm + i;
        if (m < M) {
            float4 v = make_float4(acc[i][0], acc[i][1], acc[i][2], acc[i][3]);
            *(float4*)&Cout[(size_t)m * 256 + n0 + tn] = v;
        }
    }
}

// ---------------- a_pt[m] = A[m,:] . vpt  (one row per wave) ----------------
__global__ void apt_kernel(const float* __restrict__ A,
                           const float* __restrict__ vpt,
                           float* __restrict__ apt, int M) {
    __shared__ float vs[256];
    vs[threadIdx.x] = vpt[threadIdx.x];
    __syncthreads();
    int wave = threadIdx.x >> 6;
    int lane = threadIdx.x & 63;
    int row = blockIdx.x * 4 + wave;
    if (row >= M) return;
    const float* a = A + (size_t)row * 256;
    float acc = 0.f;
    for (int i = lane; i < 256; i += 64) acc += a[i] * vs[i];
    for (int off = 32; off > 0; off >>= 1) acc += __shfl_down(acc, off);
    if (lane == 0) apt[row] = acc;
}

// ---------------- e + global max (monotonic-uint atomicMax) -----------------
__device__ __forceinline__ unsigned float_key(float f) {
    unsigned b = __float_as_uint(f);
    return (b & 0x80000000u) ? ~b : (b | 0x80000000u);
}
__device__ __forceinline__ float key_float(unsigned k) {
    return __uint_as_float((k & 0x80000000u) ? (k & 0x7FFFFFFFu) : ~k);
}

__global__ void e_max_kernel(const int* __restrict__ ci, const int* __restrict__ pi,
                             const float* __restrict__ acam, const float* __restrict__ apt,
                             float* __restrict__ ebuf, unsigned* __restrict__ maxkey, int E) {
    int i = blockIdx.x * 256 + threadIdx.x;
    float e = -INFINITY;
    if (i < E) {
        e = acam[ci[i]] + apt[pi[i]];
        ebuf[i] = e;
    }
    __shared__ float red[256];
    int t = threadIdx.x;
    red[t] = e;
    __syncthreads();
    for (int s = 128; s > 0; s >>= 1) {
        if (t < s) red[t] = fmaxf(red[t], red[t + s]);
        __syncthreads();
    }
    if (t == 0) atomicMax(maxkey, float_key(red[0]));
}

__global__ void sumexp_kernel(float* __restrict__ ebuf,
                              const unsigned* __restrict__ maxkey,
                              float* __restrict__ sumexp, int E) {
    int i = blockIdx.x * 256 + threadIdx.x;
    float mx = key_float(*maxkey);
    float p = 0.f;
    if (i < E) {
        p = expf(ebuf[i] - mx);
        ebuf[i] = p;  // store numerator in place
    }
    __shared__ float red[256];
    int t = threadIdx.x;
    red[t] = p;
    __syncthreads();
    for (int s = 128; s > 0; s >>= 1) {
        if (t < s) red[t] += red[t + s];
        __syncthreads();
    }
    if (t == 0) atomicAdd(sumexp, red[0]);
}

// ---------------- output: one edge per block ---------------------------------
__global__ void out_kernel(const int* __restrict__ ci, const int* __restrict__ pi,
                           const float* __restrict__ gcam, const float* __restrict__ gpt,
                           const float* __restrict__ bfin, const float* __restrict__ ebuf,
                           const float* __restrict__ sumexp, float* __restrict__ out, int E) {
    int e = blockIdx.x;
    int t = threadIdx.x;
    float scale = ebuf[e] / (*sumexp);
    int c = ci[e];
    int p = pi[e];
    float v = (gcam[(size_t)c * 256 + t] + gpt[(size_t)p * 256 + t] + bfin[t]) * scale;
    out[(size_t)e * 256 + t] = fmaxf(v, 0.f);
}

extern "C" void kernel_launch(void* const* d_in, const int* in_sizes, int n_in,
                              void* d_out, int out_size, void* d_ws, size_t ws_size,
                              hipStream_t stream) {
    const float* ef    = (const float*)d_in[0];
    const int*   ci    = (const int*)d_in[1];
    const int*   pi    = (const int*)d_in[2];
    const float* Wcam  = (const float*)d_in[5];
    const float* Wpt   = (const float*)d_in[6];
    const float* Wattn = (const float*)d_in[7];
    const float* Wfin  = (const float*)d_in[8];
    const float* bfin  = (const float*)d_in[9];
    float* out = (float*)d_out;
    int E = in_sizes[0] / D;

    float* ws = (float*)d_ws;
    float* cam_agg = ws;                              // 128000
    float* pt_agg  = cam_agg + (size_t)NCAM * D;      // 25,600,000
    float* CcamT   = pt_agg + (size_t)NPT * D;        // 65536
    float* Cpt     = CcamT + 65536;                   // 65536
    float* vcam    = Cpt + 65536;                     // 256
    float* vpt     = vcam + 256;                      // 256
    float* gcam    = vpt + 256;                       // 128000
    float* acam    = gcam + (size_t)NCAM * D;         // 512 (padded)
    float* gpt     = acam + 512;                      // 25,600,000
    float* apt     = gpt + (size_t)NPT * D;           // 100000
    float* ebuf    = apt + NPT;                       // E
    unsigned* maxkey = (unsigned*)(ebuf + E);
    float* sumexp  = (float*)(maxkey + 1);

    // zero the scatter targets and the two scalars
    hipMemsetAsync(cam_agg, 0, (size_t)(NCAM + NPT) * D * sizeof(float), stream);
    hipMemsetAsync(maxkey, 0, 2 * sizeof(unsigned), stream);

    scatter_kernel<<<E, 256, 0, stream>>>(ef, ci, pi, cam_agg, pt_agg, E);
    combine_weights<<<514, 256, 0, stream>>>(Wcam, Wpt, Wattn, Wfin, CcamT, Cpt, vcam, vpt);
    cam_proj<<<NCAM, 256, 0, stream>>>(cam_agg, CcamT, vcam, gcam, acam);
    dim3 g4((NPT + BM - 1) / BM, 256 / BN);
    gemm_pt<<<g4, 256, 0, stream>>>(pt_agg, Cpt, gpt, NPT);
    apt_kernel<<<(NPT + 3) / 4, 256, 0, stream>>>(pt_agg, vpt, apt, NPT);
    int eb = (E + 255) / 256;
    e_max_kernel<<<eb, 256, 0, stream>>>(ci, pi, acam, apt, ebuf, maxkey, E);
    sumexp_kernel<<<eb, 256, 0, stream>>>(ebuf, maxkey, sumexp, E);
    out_kernel<<<E, 256, 0, stream>>>(ci, pi, gcam, gpt, bfin, ebuf, sumexp, out, E);
}